// Round 3
// baseline (524.288 us; speedup 1.0000x reference)
//
#include <hip/hip_runtime.h>
#include <hip/hip_bf16.h>

#define N_NODES 100000
#define EDGES   500000
#define T_TGT   40000
#define NH      8
#define NSEM    128
#define NCLS    8
#define SLOPE   0.01f
#define NCHUNK  25      // ceil(100000/4096)
#define PPAD    36      // proj LDS row stride (elems): 72B -> 2-way conflicts (free)

#define AS1 __attribute__((address_space(1)))
#define AS3 __attribute__((address_space(3)))

typedef __attribute__((ext_vector_type(8))) __bf16 bf16x8;
typedef __attribute__((ext_vector_type(4))) float f32x4;

// ---------------------------------------------------------------------------
// 1) Fused type-wise projection via split-bf16 MFMA.
//    out[M][64] = A[M][K] @ W[64][K]^T + b for 3 types in ONE launch.
//    Precision: A = Ah+Al, W = Wh+Wl (bf16 hi + bf16 residual);
//    acc += Ah*Wh + Ah*Wl + Al*Wh  -> ~2^-16 relative error (fp32-like),
//    so output error budget is unchanged vs the fp32 vector-FMA version.
//    Why: old proj_gemm was LDS-BW-bound (2 B/FMA-lane = 2.56 GB LDS reads,
//    ~49 us with conflicts; VALUBusy 30%, 66 us). MFMA moves the math to the
//    matrix pipe; kernel becomes HBM-bound (~133 MB A reads + 26 MB writes).
//    Schedule: reg-staged (conversion needed) double-buffered LDS, loads
//    issued EARLY (sched_barrier pin), cvt+ds_write LATE after MFMA —
//    T14 async-split so HBM latency hides under compute.
//    Tile: 128 rows x 64 cols per block, 4 waves (32 rows each), BK=32.
//    LDS = 2 bufs * (Ah+Al[128][36] + Wh+Wl[64][36]) = 54 KB -> 2 blocks/CU.
// ---------------------------------------------------------------------------
__global__ __launch_bounds__(256) void proj_mfma(
        const float* __restrict__ A0, const float* __restrict__ W0,
        const float* __restrict__ b0,
        const float* __restrict__ A1, const float* __restrict__ W1,
        const float* __restrict__ b1,
        const float* __restrict__ A2, const float* __restrict__ W2,
        const float* __restrict__ b2,
        float* __restrict__ out) {
    __shared__ __bf16 Ah[2][128 * PPAD], Al[2][128 * PPAD];
    __shared__ __bf16 Wh[2][64 * PPAD],  Wl[2][64 * PPAD];
    int bx = blockIdx.x;
    const float *A, *W, *bias; int M, K, r0; float* op;
    if (bx < 313)      { A = A0; W = W0; bias = b0; M = 40000; K = 512;
                         r0 = bx * 128;         op = out; }
    else if (bx < 626) { A = A1; W = W1; bias = b1; M = 40000; K = 256;
                         r0 = (bx - 313) * 128; op = out + (size_t)40000 * 64; }
    else               { A = A2; W = W2; bias = b2; M = 20000; K = 128;
                         r0 = (bx - 626) * 128; op = out + (size_t)80000 * 64; }
    int tid = threadIdx.x;
    int wave = tid >> 6, lane = tid & 63;
    // staging map: A tile 128x32 f32 -> 16 floats/thread; W tile 64x32 -> 8
    int arow = tid >> 1;             // 0..127
    int acol = (tid & 1) * 16;       // 0 | 16
    int wrow = tid & 63;             // 0..63
    int wcol = wave * 8;             // 0,8,16,24
    const float* Arp = A + (size_t)(r0 + arow) * K + acol;
    const float* Wrp = W + (size_t)wrow * K + wcol;
    bool aval = (r0 + arow) < M;

    float4 av0, av1, av2, av3, wv0, wv1;   // named: keep static indexing
    auto gload = [&](int k0) {
        float4 z = make_float4(0.f, 0.f, 0.f, 0.f);
        av0 = aval ? *(const float4*)(Arp + k0 + 0)  : z;
        av1 = aval ? *(const float4*)(Arp + k0 + 4)  : z;
        av2 = aval ? *(const float4*)(Arp + k0 + 8)  : z;
        av3 = aval ? *(const float4*)(Arp + k0 + 12) : z;
        wv0 = *(const float4*)(Wrp + k0 + 0);
        wv1 = *(const float4*)(Wrp + k0 + 4);
    };
    auto cvt_write = [&](int buf) {
        float xa[16] = {av0.x, av0.y, av0.z, av0.w, av1.x, av1.y, av1.z, av1.w,
                        av2.x, av2.y, av2.z, av2.w, av3.x, av3.y, av3.z, av3.w};
        bf16x8 ah2[2], al2[2];
        #pragma unroll
        for (int j = 0; j < 16; j++) {
            __bf16 h = (__bf16)xa[j];
            ah2[j >> 3][j & 7] = h;
            al2[j >> 3][j & 7] = (__bf16)(xa[j] - (float)h);
        }
        *(bf16x8*)&Ah[buf][arow * PPAD + acol]     = ah2[0];
        *(bf16x8*)&Ah[buf][arow * PPAD + acol + 8] = ah2[1];
        *(bf16x8*)&Al[buf][arow * PPAD + acol]     = al2[0];
        *(bf16x8*)&Al[buf][arow * PPAD + acol + 8] = al2[1];
        float xw[8] = {wv0.x, wv0.y, wv0.z, wv0.w, wv1.x, wv1.y, wv1.z, wv1.w};
        bf16x8 wh2, wl2;
        #pragma unroll
        for (int j = 0; j < 8; j++) {
            __bf16 h = (__bf16)xw[j];
            wh2[j] = h;
            wl2[j] = (__bf16)(xw[j] - (float)h);
        }
        *(bf16x8*)&Wh[buf][wrow * PPAD + wcol] = wh2;
        *(bf16x8*)&Wl[buf][wrow * PPAD + wcol] = wl2;
    };

    int mrow = lane & 15, koff = (lane >> 4) * 8;
    f32x4 acc[2][4] = {};
    int nsteps = K >> 5;

    gload(0);
    cvt_write(0);
    __syncthreads();
    for (int t = 0; t < nsteps; t++) {
        int cur = t & 1;
        if (t + 1 < nsteps) gload((t + 1) * 32);
        __builtin_amdgcn_sched_barrier(0);   // pin loads above compute
        bf16x8 afh[2], afl[2], bfh[4], bfl[4];
        #pragma unroll
        for (int mi = 0; mi < 2; mi++) {
            int r = wave * 32 + mi * 16 + mrow;
            afh[mi] = *(const bf16x8*)&Ah[cur][r * PPAD + koff];
            afl[mi] = *(const bf16x8*)&Al[cur][r * PPAD + koff];
        }
        #pragma unroll
        for (int ni = 0; ni < 4; ni++) {
            int r = ni * 16 + mrow;
            bfh[ni] = *(const bf16x8*)&Wh[cur][r * PPAD + koff];
            bfl[ni] = *(const bf16x8*)&Wl[cur][r * PPAD + koff];
        }
        #pragma unroll
        for (int mi = 0; mi < 2; mi++)
            #pragma unroll
            for (int ni = 0; ni < 4; ni++) {
                acc[mi][ni] = __builtin_amdgcn_mfma_f32_16x16x32_bf16(afh[mi], bfh[ni], acc[mi][ni], 0, 0, 0);
                acc[mi][ni] = __builtin_amdgcn_mfma_f32_16x16x32_bf16(afh[mi], bfl[ni], acc[mi][ni], 0, 0, 0);
                acc[mi][ni] = __builtin_amdgcn_mfma_f32_16x16x32_bf16(afl[mi], bfh[ni], acc[mi][ni], 0, 0, 0);
            }
        if (t + 1 < nsteps) cvt_write(cur ^ 1);
        __syncthreads();
    }
    // epilogue: C frag layout (verified in sem_mfma): col = lane&15,
    // row = (lane>>4)*4 + j
    #pragma unroll
    for (int ni = 0; ni < 4; ni++) {
        int col = ni * 16 + mrow;
        float bv = bias[col];
        #pragma unroll
        for (int mi = 0; mi < 2; mi++) {
            int row = r0 + wave * 32 + mi * 16 + (lane >> 4) * 4;
            #pragma unroll
            for (int j = 0; j < 4; j++)
                if (row + j < M)
                    op[(size_t)(row + j) * 64 + col] = acc[mi][ni][j] + bv;
        }
    }
}

// ---------------------------------------------------------------------------
// 2) Attention projections
// ---------------------------------------------------------------------------
__global__ __launch_bounds__(256) void attn_proj(const float* __restrict__ nf,
        const float* __restrict__ na, float* __restrict__ proj) {
    __shared__ float ft[64][65];
    __shared__ float at[32][65];
    int tid = threadIdx.x;
    int n0 = blockIdx.x * 64;
    #pragma unroll
    for (int i = 0; i < 8; i++) {
        int lin = tid + i * 256;       // 0..2047
        int j = lin >> 6, d = lin & 63;
        int m = j >> 4, side = (j >> 3) & 1, h = j & 7;
        at[j][d] = na[m * 1024 + h * 128 + side * 64 + d];
    }
    #pragma unroll
    for (int i = 0; i < 4; i++) {
        int lin = tid + i * 256;       // 0..1023
        int row = lin >> 4;
        int c4 = (lin & 15) * 4;
        int gn = n0 + row;
        float4 v = make_float4(0.f, 0.f, 0.f, 0.f);
        if (gn < N_NODES) v = *(const float4*)(nf + (size_t)gn * 64 + c4);
        ft[row][c4 + 0] = v.x; ft[row][c4 + 1] = v.y;
        ft[row][c4 + 2] = v.z; ft[row][c4 + 3] = v.w;
    }
    __syncthreads();
    int node = tid >> 2;   // 0..63
    int jg = tid & 3;      // output group of 8
    float acc[8] = {};
    for (int d = 0; d < 64; d++) {
        float f = ft[node][d];
        #pragma unroll
        for (int jj = 0; jj < 8; jj++)
            acc[jj] = fmaf(f, at[jg * 8 + jj][d], acc[jj]);
    }
    int gn = n0 + node;
    if (gn < N_NODES) {
        float4 o0 = make_float4(acc[0], acc[1], acc[2], acc[3]);
        float4 o1 = make_float4(acc[4], acc[5], acc[6], acc[7]);
        *(float4*)(proj + (size_t)gn * 32 + jg * 8) = o0;
        *(float4*)(proj + (size_t)gn * 32 + jg * 8 + 4) = o1;
    }
}

// ---------------------------------------------------------------------------
// 3) CSR build helpers
// ---------------------------------------------------------------------------
__global__ void hist_targets(const int* __restrict__ tgt, int* __restrict__ tcnt) {
    int i = blockIdx.x * 256 + threadIdx.x;
    if (i < T_TGT) atomicAdd(&tcnt[tgt[i]], 1);
}

__global__ void hist_edges(const int* __restrict__ mp, const int* __restrict__ tcnt,
                           int* __restrict__ ecnt) {
    int e = blockIdx.x * 256 + threadIdx.x;
    if (e < EDGES) {
        int dst = mp[2 * e + 1];
        if (tcnt[dst] > 0) atomicAdd(&ecnt[dst], 1);
    }
}

// --- hierarchical exclusive scan over 3 length-N arrays --------------------
// phase A: per-chunk (4096) block sums
__global__ __launch_bounds__(1024) void scan_partial(const int* __restrict__ counts,
        int* __restrict__ partials) {
    int a = blockIdx.y, bx = blockIdx.x;
    const int* in = counts + (size_t)a * N_NODES;
    int base = bx * 4096 + threadIdx.x * 4;
    int s = 0;
    #pragma unroll
    for (int i = 0; i < 4; i++) {
        int idx = base + i;
        if (idx < N_NODES) s += in[idx];
    }
    #pragma unroll
    for (int off = 32; off; off >>= 1) s += __shfl_xor(s, off);
    __shared__ int red[16];
    int lane = threadIdx.x & 63, w = threadIdx.x >> 6;
    if (lane == 0) red[w] = s;
    __syncthreads();
    if (threadIdx.x < 16) {
        int x = red[threadIdx.x];
        #pragma unroll
        for (int off = 8; off; off >>= 1) x += __shfl_xor(x, off);
        if (threadIdx.x == 0) partials[a * 32 + bx] = x;
    }
}

// phase B: scan the chunk sums (3 waves, one per array); write array totals
__global__ void scan_partials(const int* __restrict__ partials,
        int* __restrict__ choff, int* __restrict__ offs) {
    int w = threadIdx.x >> 6, lane = threadIdx.x & 63;
    if (w < 3 && lane < 32) {
        int v = (lane < NCHUNK) ? partials[w * 32 + lane] : 0;
        int x = v;
        #pragma unroll
        for (int off = 1; off < 32; off <<= 1) {
            int y = __shfl_up(x, off);
            if (lane >= off) x += y;
        }
        if (lane < NCHUNK) choff[w * 32 + lane] = x - v;
        if (lane == NCHUNK - 1) offs[(size_t)w * (N_NODES + 1) + N_NODES] = x;
    }
}

// phase C: local scan + chunk offset -> offs & curs
__global__ __launch_bounds__(1024) void scan_final(const int* __restrict__ counts,
        const int* __restrict__ choff, int* __restrict__ offs, int* __restrict__ curs) {
    int a = blockIdx.y, bx = blockIdx.x;
    const int* in = counts + (size_t)a * N_NODES;
    int* out = offs + (size_t)a * (N_NODES + 1);
    int* cur = curs + (size_t)a * N_NODES;
    int tid = threadIdx.x, lane = tid & 63, w = tid >> 6;
    int base = bx * 4096 + tid * 4;
    int v[4], sum4 = 0;
    #pragma unroll
    for (int i = 0; i < 4; i++) {
        int idx = base + i;
        v[i] = (idx < N_NODES) ? in[idx] : 0;
        sum4 += v[i];
    }
    int x = sum4;
    #pragma unroll
    for (int off = 1; off < 64; off <<= 1) {
        int y = __shfl_up(x, off);
        if (lane >= off) x += y;
    }
    __shared__ int wred[16], wexc[16];
    if (lane == 63) wred[w] = x;
    __syncthreads();
    if (tid < 16) {
        int s = wred[tid], xs = s;
        #pragma unroll
        for (int off = 1; off < 16; off <<= 1) {
            int y = __shfl_up(xs, off);
            if (tid >= off) xs += y;
        }
        wexc[tid] = xs - s;
    }
    __syncthreads();
    int off0 = choff[a * 32 + bx] + wexc[w] + (x - sum4);
    int run = 0;
    #pragma unroll
    for (int i = 0; i < 4; i++) {
        int idx = base + i;
        if (idx < N_NODES) { out[idx] = off0 + run; cur[idx] = off0 + run; }
        run += v[i];
    }
}

__global__ void scatter_targets(const int* __restrict__ tgt, int* __restrict__ tcur,
                                int* __restrict__ tlist) {
    int i = blockIdx.x * 256 + threadIdx.x;
    if (i < T_TGT) {
        int n = tgt[i];
        int p = atomicAdd(&tcur[n], 1);
        tlist[p] = i;
    }
}

// scatter + edge attention numerator exp(leaky(score)) — unshifted exp is
// overflow-safe (score std ~1.1). No denominator atomics: agg sums them.
__global__ __launch_bounds__(256) void scatter_score(const int* __restrict__ mp,
        const int* __restrict__ tcnt, int* __restrict__ ecur,
        int* __restrict__ elist, __bf16* __restrict__ exs,
        const float* __restrict__ proj, int m) {
    int e = blockIdx.x * 256 + threadIdx.x;
    if (e >= EDGES) return;
    int src = mp[2 * e], dst = mp[2 * e + 1];
    if (tcnt[dst] <= 0) return;
    int p = atomicAdd(&ecur[dst], 1);
    elist[p] = src;
    const float* adp = proj + (size_t)dst * 32 + m * 16;
    const float* asp = proj + (size_t)src * 32 + m * 16 + 8;
    float4 ad0 = *(const float4*)(adp), ad1 = *(const float4*)(adp + 4);
    float4 as0 = *(const float4*)(asp), as1 = *(const float4*)(asp + 4);
    float ads[8] = {ad0.x, ad0.y, ad0.z, ad0.w, ad1.x, ad1.y, ad1.z, ad1.w};
    float ass[8] = {as0.x, as0.y, as0.z, as0.w, as1.x, as1.y, as1.z, as1.w};
    bf16x8 exv;
    #pragma unroll
    for (int h = 0; h < 8; h++) {
        float sc = ads[h] + ass[h];
        sc = sc > 0.f ? sc : SLOPE * sc;
        exv[h] = (__bf16)__expf(sc);
    }
    *(bf16x8*)(exs + (size_t)p * 8) = exv;
}

__global__ void build_ulist(const int* __restrict__ tcnt, int* __restrict__ ulist,
                            int* __restrict__ ucount) {
    int n = blockIdx.x * 256 + threadIdx.x;
    if (n < N_NODES && tcnt[n] > 0) {
        int u = atomicAdd(ucount, 1);
        ulist[u] = n;
    }
}

__global__ void cvt_bf16(const float* __restrict__ in, __bf16* __restrict__ out, int n) {
    int i = blockIdx.x * 256 + threadIdx.x;
    if (i < n) out[i] = (__bf16)in[i];
}

// ---------------------------------------------------------------------------
// 4) Aggregation: one wave per (metapath, target-node); single edge pass.
//    Denominator accumulated in-wave (uniform), normalize at the end.
// ---------------------------------------------------------------------------
__global__ __launch_bounds__(256) void agg_kernel(
        const int* __restrict__ ulist, const int* __restrict__ ctrl_i,
        const int* __restrict__ offs,   // [3][N+1]: m0, m1, targets
        const int* __restrict__ esrc,   // [2][E]
        const __bf16* __restrict__ exs, // [2][E][8]
        const float* __restrict__ nf,
        const int* __restrict__ tlist,
        __bf16* hb0, __bf16* hb1) {
    int m = blockIdx.y;
    int wslot = blockIdx.x * 4 + (threadIdx.x >> 6);
    int lane = threadIdx.x & 63;
    int ucount = ctrl_i[0];
    if (wslot >= ucount) return;        // uniform per wave
    int node = __builtin_amdgcn_readfirstlane(ulist[wslot]);  // -> SGPR
    const int* eo = offs + (size_t)m * (N_NODES + 1);
    int e0 = eo[node], e1 = eo[node + 1];
    const int* srcs = esrc + (size_t)m * EDGES;
    const __bf16* exm = exs + (size_t)m * EDGES * 8;
    float acc[8] = {};
    float dacc[8] = {};
    for (int e = e0; e < e1; e++) {
        int s = srcs[e];                               // uniform -> s_load
        bf16x8 pb = *(const bf16x8*)(exm + (size_t)e * 8);  // uniform 16B
        float v = nf[(size_t)s * 64 + lane];           // coalesced vector load
        #pragma unroll
        for (int h = 0; h < 8; h++) {
            float pw = (float)pb[h];
            dacc[h] += pw;
            acc[h] = fmaf(pw, v, acc[h]);
        }
    }
    #pragma unroll
    for (int h = 0; h < 8; h++)
        acc[h] *= (dacc[h] > 0.f) ? 1.0f / dacc[h] : 0.f;
    // write (bf16) to every target slot mapping to this node
    const int* to = offs + (size_t)2 * (N_NODES + 1);
    int t0 = to[node], t1 = to[node + 1];
    __bf16* hb = (m == 0) ? hb0 : hb1;
    for (int ti = t0; ti < t1; ti++) {
        int t = tlist[ti];
        __bf16* dst = hb + (size_t)t * 512;
        #pragma unroll
        for (int h = 0; h < 8; h++) dst[h * 64 + lane] = (__bf16)acc[h];
    }
}

// ---------------------------------------------------------------------------
// 5) Semantic attention scores via bf16 MFMA.
//    2-phase async pipeline: A (hb rows) and B (Wsem) are staged into
//    double-buffered LDS with global_load_lds (width 16) — the DMA path
//    bypasses VGPRs entirely, so the compiler cannot collapse the prefetch.
//    BM=64, BN=128, BK=64; LDS = 2*(8K + 16K) = 48 KB -> 3 blocks/CU.
// ---------------------------------------------------------------------------
__global__ __launch_bounds__(256) void sem_mfma(
        const __bf16* __restrict__ hb,   // [2][T][512]
        const __bf16* __restrict__ Wb,   // [128][512]
        const float* __restrict__ bsem, const float* __restrict__ a_sem,
        float* __restrict__ scores) {
    __shared__ __bf16 As[2][64 * 64];    // 8 KB per buffer
    __shared__ __bf16 Bs[2][128 * 64];   // 16 KB per buffer
    int m = blockIdx.y;
    int tid = threadIdx.x;
    int wave = tid >> 6, lane = tid & 63;
    const __bf16* A0 = hb + (size_t)m * T_TGT * 512 + (size_t)blockIdx.x * 64 * 512;

    int srow = lane >> 3;            // 0..7
    int scol = (lane & 7) * 8;       // element col 0..56

    auto stage = [&](int buf, int k0) {
        #pragma unroll
        for (int j = 0; j < 2; j++) {           // A: 64 rows x 64 k
            int row = j * 32 + wave * 8 + srow;
            const __bf16* gp = A0 + (size_t)row * 512 + k0 + scol;
            __bf16* lp = &As[buf][(j * 32 + wave * 8) * 64];
            __builtin_amdgcn_global_load_lds((const AS1 void*)gp,
                                             (AS3 void*)lp, 16, 0, 0);
        }
        #pragma unroll
        for (int j = 0; j < 4; j++) {           // B: 128 rows x 64 k
            int row = j * 32 + wave * 8 + srow;
            const __bf16* gp = Wb + (size_t)row * 512 + k0 + scol;
            __bf16* lp = &Bs[buf][(j * 32 + wave * 8) * 64];
            __builtin_amdgcn_global_load_lds((const AS1 void*)gp,
                                             (AS3 void*)lp, 16, 0, 0);
        }
    };

    int mrow = lane & 15;
    int kq = lane >> 4;              // 0..3
    f32x4 acc[4][2] = {};

    stage(0, 0);
    __syncthreads();                 // drains vmcnt: buf0 ready
    for (int t = 0; t < 8; t++) {
        int cur = t & 1;
        if (t < 7) stage(cur ^ 1, (t + 1) * 64);
        __builtin_amdgcn_sched_barrier(0);   // keep stage issues above compute
        const __bf16* Ab = &As[cur][0];
        const __bf16* Bb = &Bs[cur][0];
        #pragma unroll
        for (int kk = 0; kk < 2; kk++) {
            int ko = kk * 32 + kq * 8;
            bf16x8 a[4], b[2];
            #pragma unroll
            for (int r = 0; r < 4; r++)
                a[r] = *(const bf16x8*)(Ab + (r * 16 + mrow) * 64 + ko);
            #pragma unroll
            for (int c = 0; c < 2; c++)
                b[c] = *(const bf16x8*)(Bb + (wave * 32 + c * 16 + mrow) * 64 + ko);
            #pragma unroll
            for (int r = 0; r < 4; r++)
                #pragma unroll
                for (int c = 0; c < 2; c++)
                    acc[r][c] = __builtin_amdgcn_mfma_f32_16x16x32_bf16(a[r], b[c], acc[r][c], 0, 0, 0);
        }
        __syncthreads();             // stage(t+1) done + all reads of buf done
    }

    int n0 = wave * 32;
    float tot = 0.f;
    #pragma unroll
    for (int c = 0; c < 2; c++) {
        int col = n0 + c * 16 + (lane & 15);
        float bs = bsem[col], as = a_sem[col];
        #pragma unroll
        for (int r = 0; r < 4; r++)
            #pragma unroll
            for (int j = 0; j < 4; j++) {
                float x = acc[r][c][j] + bs;
                float th = 1.f - 2.f / (__expf(2.f * x) + 1.f);  // tanh, inf-safe
                tot += th * as;
            }
    }
    __shared__ float red[256];
    red[threadIdx.x] = tot;
    __syncthreads();
    for (int s = 128; s; s >>= 1) {
        if (threadIdx.x < s) red[threadIdx.x] += red[threadIdx.x + s];
        __syncthreads();
    }
    if (threadIdx.x == 0) atomicAdd(&scores[m], red[0]);
}

__global__ void beta_kernel(const float* __restrict__ scores, float* __restrict__ beta) {
    if (threadIdx.x == 0) {
        float s0 = scores[0] / (float)T_TGT;
        float s1 = scores[1] / (float)T_TGT;
        float mx = fmaxf(s0, s1);
        float e0 = __expf(s0 - mx), e1 = __expf(s1 - mx);
        float inv = 1.f / (e0 + e1);
        beta[0] = e0 * inv;
        beta[1] = e1 * inv;
    }
}

// ---------------------------------------------------------------------------
// 6) embeddings = b0*h0 + b1*h1 (bf16 in, f32 out) + cls logits.
// ---------------------------------------------------------------------------
__global__ __launch_bounds__(256) void emb_cls(
        const __bf16* __restrict__ hb0, const __bf16* __restrict__ hb1,
        const float* __restrict__ beta, const float* __restrict__ Wcls,
        const float* __restrict__ bcls, float* out_cls, float* out_emb) {
    __shared__ float Wl[8 * 512];
    int tid = threadIdx.x;
    #pragma unroll
    for (int i = 0; i < 16; i++) Wl[tid + i * 256] = Wcls[tid + i * 256];
    __syncthreads();
    int t = blockIdx.x * 4 + (tid >> 6);
    int lane = tid & 63;
    float b0 = beta[0], b1 = beta[1];
    bf16x8 v0 = *(const bf16x8*)(hb0 + (size_t)t * 512 + lane * 8);
    bf16x8 v1 = *(const bf16x8*)(hb1 + (size_t)t * 512 + lane * 8);
    float e[8];
    #pragma unroll
    for (int j = 0; j < 8; j++) e[j] = b0 * (float)v0[j] + b1 * (float)v1[j];
    float* ep = out_emb + (size_t)t * 512 + lane * 8;
    *(float4*)(ep + 0) = make_float4(e[0], e[1], e[2], e[3]);
    *(float4*)(ep + 4) = make_float4(e[4], e[5], e[6], e[7]);
    float pc[8];
    #pragma unroll
    for (int c = 0; c < 8; c++) {
        float4 w0 = *(const float4*)(Wl + c * 512 + lane * 8);
        float4 w1 = *(const float4*)(Wl + c * 512 + lane * 8 + 4);
        pc[c] = e[0] * w0.x + e[1] * w0.y + e[2] * w0.z + e[3] * w0.w
              + e[4] * w1.x + e[5] * w1.y + e[6] * w1.z + e[7] * w1.w;
    }
    #pragma unroll
    for (int off = 32; off; off >>= 1)
        #pragma unroll
        for (int c = 0; c < 8; c++) pc[c] += __shfl_xor(pc[c], off);
    if (lane == 0) {
        #pragma unroll
        for (int c = 0; c < 8; c++) out_cls[(size_t)t * 8 + c] = pc[c] + bcls[c];
    }
}

// ---------------------------------------------------------------------------
extern "C" void kernel_launch(void* const* d_in, const int* in_sizes, int n_in,
                              void* d_out, int out_size, void* d_ws, size_t ws_size,
                              hipStream_t stream) {
    const int* target = (const int*)d_in[0];
    const int* mp0 = (const int*)d_in[1];
    const int* mp1 = (const int*)d_in[2];
    // d_in[3] node_type_mapping unused (types are contiguous ranges)
    const float* feat0 = (const float*)d_in[4];
    const float* W0 = (const float*)d_in[5];
    const float* b0 = (const float*)d_in[6];
    const float* feat1 = (const float*)d_in[7];
    const float* W1 = (const float*)d_in[8];
    const float* b1 = (const float*)d_in[9];
    const float* feat2 = (const float*)d_in[10];
    const float* W2 = (const float*)d_in[11];
    const float* b2 = (const float*)d_in[12];
    const float* natt = (const float*)d_in[13];
    const float* Wsem = (const float*)d_in[14];
    const float* bsem = (const float*)d_in[15];
    const float* asem = (const float*)d_in[16];
    const float* Wcls = (const float*)d_in[17];
    const float* bcls = (const float*)d_in[18];

    char* ws = (char*)d_ws;
    size_t off = 0;
    auto alloc = [&](size_t bytes) -> void* {
        void* p = ws + off;
        off += (bytes + 31) & ~(size_t)31;
        return p;
    };
    float* nf    = (float*)alloc((size_t)N_NODES * 64 * 4);   // 25.6 MB
    float* proj  = (float*)alloc((size_t)N_NODES * 32 * 4);   // 12.8 MB
    int* counts3 = (int*)alloc((size_t)3 * N_NODES * 4);
    int* offs3   = (int*)alloc((size_t)3 * (N_NODES + 1) * 4);
    int* curs3   = (int*)alloc((size_t)3 * N_NODES * 4);
    int* tlist   = (int*)alloc((size_t)T_TGT * 4);
    int* ulist   = (int*)alloc((size_t)N_NODES * 4);
    int* esrc    = (int*)alloc((size_t)2 * EDGES * 4);        // 4 MB
    __bf16* exs  = (__bf16*)alloc((size_t)2 * EDGES * 8 * 2); // 16 MB
    int* partials = (int*)alloc((size_t)3 * 32 * 4);
    int* choff    = (int*)alloc((size_t)3 * 32 * 4);
    int* ctrl    = (int*)alloc(64);
    __bf16* Wsem_b = (__bf16*)alloc((size_t)NSEM * 512 * 2);  // 128 KB
    __bf16* hb   = (__bf16*)alloc((size_t)2 * T_TGT * 512 * 2); // 81.9 MB
    if (off > ws_size) return;  // ws too small: fail loudly (output stays poisoned)

    float* out_cls = (float*)d_out;
    float* out_emb = out_cls + (size_t)T_TGT * NCLS;
    __bf16* hb0 = hb;
    __bf16* hb1 = hb + (size_t)T_TGT * 512;
    float* ctrl_f = (float*)ctrl;
    float* scores = ctrl_f + 1;             // ctrl[0] = ucount
    float* beta = ctrl_f + 3;

    hipMemsetAsync(counts3, 0, (size_t)3 * N_NODES * 4, stream);
    hipMemsetAsync(ctrl, 0, 64, stream);

    proj_mfma<<<dim3(783), 256, 0, stream>>>(feat0, W0, b0, feat1, W1, b1,
                                             feat2, W2, b2, nf);
    attn_proj<<<dim3(1563), 256, 0, stream>>>(nf, natt, proj);
    cvt_bf16<<<dim3(256), 256, 0, stream>>>(Wsem, Wsem_b, NSEM * 512);

    hist_targets<<<dim3(157), 256, 0, stream>>>(target, counts3 + 2 * N_NODES);
    hist_edges<<<dim3(1954), 256, 0, stream>>>(mp0, counts3 + 2 * N_NODES, counts3);
    hist_edges<<<dim3(1954), 256, 0, stream>>>(mp1, counts3 + 2 * N_NODES, counts3 + N_NODES);
    scan_partial<<<dim3(NCHUNK, 3), 1024, 0, stream>>>(counts3, partials);
    scan_partials<<<dim3(1), 192, 0, stream>>>(partials, choff, offs3);
    scan_final<<<dim3(NCHUNK, 3), 1024, 0, stream>>>(counts3, choff, offs3, curs3);
    scatter_targets<<<dim3(157), 256, 0, stream>>>(target, curs3 + 2 * N_NODES, tlist);
    scatter_score<<<dim3(1954), 256, 0, stream>>>(mp0, counts3 + 2 * N_NODES, curs3,
                                                  esrc, exs, proj, 0);
    scatter_score<<<dim3(1954), 256, 0, stream>>>(mp1, counts3 + 2 * N_NODES, curs3 + N_NODES,
                                                  esrc + EDGES, exs + (size_t)EDGES * 8, proj, 1);
    build_ulist<<<dim3(391), 256, 0, stream>>>(counts3 + 2 * N_NODES, ulist, ctrl);

    agg_kernel<<<dim3(10000, 2), 256, 0, stream>>>(ulist, ctrl, offs3, esrc, exs,
                                                   nf, tlist, hb0, hb1);
    sem_mfma<<<dim3(625, 2), 256, 0, stream>>>(hb, Wsem_b, bsem, asem, scores);
    beta_kernel<<<dim3(1), 64, 0, stream>>>(scores, beta);
    emb_cls<<<dim3(10000), 256, 0, stream>>>(hb0, hb1, beta, Wcls, bcls, out_cls, out_emb);
}

// Round 4
// 476.932 us; speedup vs baseline: 1.0993x; 1.0993x over previous
//
#include <hip/hip_runtime.h>
#include <hip/hip_bf16.h>

#define N_NODES 100000
#define EDGES   500000
#define T_TGT   40000
#define NH      8
#define NSEM    128
#define NCLS    8
#define SLOPE   0.01f
#define NCHUNK  25      // ceil(100000/4096)

#define AS1 __attribute__((address_space(1)))
#define AS3 __attribute__((address_space(3)))

typedef __attribute__((ext_vector_type(8))) __bf16 bf16x8;
typedef __attribute__((ext_vector_type(4))) float f32x4;

// ---------------------------------------------------------------------------
// 0) One-shot split of W0/W1/W2 into bf16 hi + bf16 residual (57344 elems).
//    Removes all W conversion from the proj hot loop.
// ---------------------------------------------------------------------------
__global__ void cvt_whl(const float* __restrict__ W0, const float* __restrict__ W1,
                        const float* __restrict__ W2,
                        __bf16* __restrict__ wh, __bf16* __restrict__ wl) {
    int i = blockIdx.x * 256 + threadIdx.x;
    float v;
    if (i < 32768) v = W0[i];
    else if (i < 49152) v = W1[i - 32768];
    else if (i < 57344) v = W2[i - 49152];
    else return;
    __bf16 h = (__bf16)v;
    wh[i] = h;
    wl[i] = (__bf16)(v - (float)h);
}

// ---------------------------------------------------------------------------
// 1) Fused type-wise projection via split-bf16 MFMA, sem_mfma-style pipeline.
//    out[M][64] = A[M][K] @ W[64][K]^T + b, 3 types in one launch.
//    acc += Ah*Wh + Ah*Wl + Al*Wh  (~2^-16 rel err, fp32-equivalent).
//    R3 post-mortem: reg-staged cvt_write serialized vmcnt(0)+cvt+ds_write
//    into every step (MfmaUtil 4.2%, 116 us). Fix: A staged RAW fp32 via
//    global_load_lds DMA (double-buffered, compiler can't collapse it);
//    hi/lo split happens in registers between LDS-read and MFMA; W hi/lo
//    pre-split by cvt_whl. LDS 2*(16K+4K+4K)=48 KB -> 3 blocks/CU.
//    Bank fix (rule 21, both-sides): LDS linear, source col pre-swizzled
//    col ^= (row&3)<<3 (elems), read applies same XOR -> 16-way -> 4-way.
//    Tile: 128 rows x 64 cols, 4 waves x (32 rows), BK=32.
// ---------------------------------------------------------------------------
__global__ __launch_bounds__(256) void proj_mfma(
        const float* __restrict__ A0, const float* __restrict__ b0,
        const float* __restrict__ A1, const float* __restrict__ b1,
        const float* __restrict__ A2, const float* __restrict__ b2,
        const __bf16* __restrict__ whb, const __bf16* __restrict__ wlb,
        float* __restrict__ out) {
    __shared__ float  Asb[2][128 * 32];   // 16 KB per buffer
    __shared__ __bf16 Whs[2][64 * 32];    // 4 KB per buffer
    __shared__ __bf16 Wls[2][64 * 32];    // 4 KB per buffer
    int bx = blockIdx.x;
    const float *A, *bias; int M, K, r0, woff; float* op;
    if (bx < 313)      { A = A0; bias = b0; M = 40000; K = 512; woff = 0;
                         r0 = bx * 128;         op = out; }
    else if (bx < 626) { A = A1; bias = b1; M = 40000; K = 256; woff = 32768;
                         r0 = (bx - 313) * 128; op = out + (size_t)40000 * 64; }
    else               { A = A2; bias = b2; M = 20000; K = 128; woff = 49152;
                         r0 = (bx - 626) * 128; op = out + (size_t)80000 * 64; }
    const __bf16* Whp = whb + woff;
    const __bf16* Wlp = wlb + woff;
    int tid = threadIdx.x;
    int wave = tid >> 6, lane = tid & 63;

    auto stage = [&](int buf, int k0) {
        // A: 128 rows x 32 f32 (128 B/row). 4 DMA/wave, 8 rows each.
        #pragma unroll
        for (int j = 0; j < 4; j++) {
            int rl = j * 32 + wave * 8 + (lane >> 3);   // LDS row 0..127
            int g = r0 + rl; if (g > M - 1) g = M - 1;  // tail clamp (masked at C-write)
            int col = k0 + (((lane & 7) * 4) ^ ((rl & 3) << 3));  // pre-swizzled src
            const float* gp = A + (size_t)g * K + col;
            float* lp = &Asb[buf][(j * 32 + wave * 8) * 32];
            __builtin_amdgcn_global_load_lds((const AS1 void*)gp,
                                             (AS3 void*)lp, 16, 0, 0);
        }
        // Wh/Wl: 64 rows x 32 bf16 (64 B/row). 1 DMA/wave each, 16 rows.
        {
            int rl = wave * 16 + (lane >> 2);
            int col = k0 + (((lane & 3) * 8) ^ ((rl & 3) << 3));
            const __bf16* gph = Whp + (size_t)rl * K + col;
            __builtin_amdgcn_global_load_lds((const AS1 void*)gph,
                    (AS3 void*)&Whs[buf][(wave * 16) * 32], 16, 0, 0);
            const __bf16* gpl = Wlp + (size_t)rl * K + col;
            __builtin_amdgcn_global_load_lds((const AS1 void*)gpl,
                    (AS3 void*)&Wls[buf][(wave * 16) * 32], 16, 0, 0);
        }
    };

    int mrow = lane & 15, kq = lane >> 4;
    f32x4 acc[2][4] = {};
    int nsteps = K >> 5;

    stage(0, 0);
    __syncthreads();
    for (int t = 0; t < nsteps; t++) {
        int cur = t & 1;
        if (t + 1 < nsteps) stage(cur ^ 1, (t + 1) * 32);
        __builtin_amdgcn_sched_barrier(0);   // keep DMA issues above compute
        bf16x8 ah[2], al[2], wh[4], wl[4];
        #pragma unroll
        for (int mi = 0; mi < 2; mi++) {
            int r = wave * 32 + mi * 16 + mrow;
            int off = (kq * 8) ^ ((r & 3) << 3);        // un-swizzle on read
            const float* p = &Asb[cur][r * 32 + off];
            f32x4 v0 = *(const f32x4*)p;
            f32x4 v1 = *(const f32x4*)(p + 4);
            #pragma unroll
            for (int j = 0; j < 4; j++) {
                __bf16 h0 = (__bf16)v0[j];
                ah[mi][j] = h0; al[mi][j] = (__bf16)(v0[j] - (float)h0);
                __bf16 h1 = (__bf16)v1[j];
                ah[mi][j + 4] = h1; al[mi][j + 4] = (__bf16)(v1[j] - (float)h1);
            }
        }
        #pragma unroll
        for (int ni = 0; ni < 4; ni++) {
            int r = ni * 16 + mrow;
            int off = (kq * 8) ^ ((r & 3) << 3);
            wh[ni] = *(const bf16x8*)&Whs[cur][r * 32 + off];
            wl[ni] = *(const bf16x8*)&Wls[cur][r * 32 + off];
        }
        #pragma unroll
        for (int mi = 0; mi < 2; mi++)
            #pragma unroll
            for (int ni = 0; ni < 4; ni++) {
                acc[mi][ni] = __builtin_amdgcn_mfma_f32_16x16x32_bf16(ah[mi], wh[ni], acc[mi][ni], 0, 0, 0);
                acc[mi][ni] = __builtin_amdgcn_mfma_f32_16x16x32_bf16(ah[mi], wl[ni], acc[mi][ni], 0, 0, 0);
                acc[mi][ni] = __builtin_amdgcn_mfma_f32_16x16x32_bf16(al[mi], wh[ni], acc[mi][ni], 0, 0, 0);
            }
        __syncthreads();
    }
    // epilogue: C frag layout: col = lane&15, row = (lane>>4)*4 + j
    #pragma unroll
    for (int ni = 0; ni < 4; ni++) {
        int col = ni * 16 + mrow;
        float bv = bias[col];
        #pragma unroll
        for (int mi = 0; mi < 2; mi++) {
            int row = r0 + wave * 32 + mi * 16 + (lane >> 4) * 4;
            #pragma unroll
            for (int j = 0; j < 4; j++)
                if (row + j < M)
                    op[(size_t)(row + j) * 64 + col] = acc[mi][ni][j] + bv;
        }
    }
}

// ---------------------------------------------------------------------------
// 2) Attention projections
// ---------------------------------------------------------------------------
__global__ __launch_bounds__(256) void attn_proj(const float* __restrict__ nf,
        const float* __restrict__ na, float* __restrict__ proj) {
    __shared__ float ft[64][65];
    __shared__ float at[32][65];
    int tid = threadIdx.x;
    int n0 = blockIdx.x * 64;
    #pragma unroll
    for (int i = 0; i < 8; i++) {
        int lin = tid + i * 256;       // 0..2047
        int j = lin >> 6, d = lin & 63;
        int m = j >> 4, side = (j >> 3) & 1, h = j & 7;
        at[j][d] = na[m * 1024 + h * 128 + side * 64 + d];
    }
    #pragma unroll
    for (int i = 0; i < 4; i++) {
        int lin = tid + i * 256;       // 0..1023
        int row = lin >> 4;
        int c4 = (lin & 15) * 4;
        int gn = n0 + row;
        float4 v = make_float4(0.f, 0.f, 0.f, 0.f);
        if (gn < N_NODES) v = *(const float4*)(nf + (size_t)gn * 64 + c4);
        ft[row][c4 + 0] = v.x; ft[row][c4 + 1] = v.y;
        ft[row][c4 + 2] = v.z; ft[row][c4 + 3] = v.w;
    }
    __syncthreads();
    int node = tid >> 2;   // 0..63
    int jg = tid & 3;      // output group of 8
    float acc[8] = {};
    for (int d = 0; d < 64; d++) {
        float f = ft[node][d];
        #pragma unroll
        for (int jj = 0; jj < 8; jj++)
            acc[jj] = fmaf(f, at[jg * 8 + jj][d], acc[jj]);
    }
    int gn = n0 + node;
    if (gn < N_NODES) {
        float4 o0 = make_float4(acc[0], acc[1], acc[2], acc[3]);
        float4 o1 = make_float4(acc[4], acc[5], acc[6], acc[7]);
        *(float4*)(proj + (size_t)gn * 32 + jg * 8) = o0;
        *(float4*)(proj + (size_t)gn * 32 + jg * 8 + 4) = o1;
    }
}

// ---------------------------------------------------------------------------
// 3) CSR build helpers
// ---------------------------------------------------------------------------
__global__ void hist_targets(const int* __restrict__ tgt, int* __restrict__ tcnt) {
    int i = blockIdx.x * 256 + threadIdx.x;
    if (i < T_TGT) atomicAdd(&tcnt[tgt[i]], 1);
}

__global__ void hist_edges(const int* __restrict__ mp, const int* __restrict__ tcnt,
                           int* __restrict__ ecnt) {
    int e = blockIdx.x * 256 + threadIdx.x;
    if (e < EDGES) {
        int dst = mp[2 * e + 1];
        if (tcnt[dst] > 0) atomicAdd(&ecnt[dst], 1);
    }
}

// --- hierarchical exclusive scan over 3 length-N arrays --------------------
// phase A: per-chunk (4096) block sums
__global__ __launch_bounds__(1024) void scan_partial(const int* __restrict__ counts,
        int* __restrict__ partials) {
    int a = blockIdx.y, bx = blockIdx.x;
    const int* in = counts + (size_t)a * N_NODES;
    int base = bx * 4096 + threadIdx.x * 4;
    int s = 0;
    #pragma unroll
    for (int i = 0; i < 4; i++) {
        int idx = base + i;
        if (idx < N_NODES) s += in[idx];
    }
    #pragma unroll
    for (int off = 32; off; off >>= 1) s += __shfl_xor(s, off);
    __shared__ int red[16];
    int lane = threadIdx.x & 63, w = threadIdx.x >> 6;
    if (lane == 0) red[w] = s;
    __syncthreads();
    if (threadIdx.x < 16) {
        int x = red[threadIdx.x];
        #pragma unroll
        for (int off = 8; off; off >>= 1) x += __shfl_xor(x, off);
        if (threadIdx.x == 0) partials[a * 32 + bx] = x;
    }
}

// phase B: scan the chunk sums (3 waves, one per array); write array totals
__global__ void scan_partials(const int* __restrict__ partials,
        int* __restrict__ choff, int* __restrict__ offs) {
    int w = threadIdx.x >> 6, lane = threadIdx.x & 63;
    if (w < 3 && lane < 32) {
        int v = (lane < NCHUNK) ? partials[w * 32 + lane] : 0;
        int x = v;
        #pragma unroll
        for (int off = 1; off < 32; off <<= 1) {
            int y = __shfl_up(x, off);
            if (lane >= off) x += y;
        }
        if (lane < NCHUNK) choff[w * 32 + lane] = x - v;
        if (lane == NCHUNK - 1) offs[(size_t)w * (N_NODES + 1) + N_NODES] = x;
    }
}

// phase C: local scan + chunk offset -> offs & curs
__global__ __launch_bounds__(1024) void scan_final(const int* __restrict__ counts,
        const int* __restrict__ choff, int* __restrict__ offs, int* __restrict__ curs) {
    int a = blockIdx.y, bx = blockIdx.x;
    const int* in = counts + (size_t)a * N_NODES;
    int* out = offs + (size_t)a * (N_NODES + 1);
    int* cur = curs + (size_t)a * N_NODES;
    int tid = threadIdx.x, lane = tid & 63, w = tid >> 6;
    int base = bx * 4096 + tid * 4;
    int v[4], sum4 = 0;
    #pragma unroll
    for (int i = 0; i < 4; i++) {
        int idx = base + i;
        v[i] = (idx < N_NODES) ? in[idx] : 0;
        sum4 += v[i];
    }
    int x = sum4;
    #pragma unroll
    for (int off = 1; off < 64; off <<= 1) {
        int y = __shfl_up(x, off);
        if (lane >= off) x += y;
    }
    __shared__ int wred[16], wexc[16];
    if (lane == 63) wred[w] = x;
    __syncthreads();
    if (tid < 16) {
        int s = wred[tid], xs = s;
        #pragma unroll
        for (int off = 1; off < 16; off <<= 1) {
            int y = __shfl_up(xs, off);
            if (tid >= off) xs += y;
        }
        wexc[tid] = xs - s;
    }
    __syncthreads();
    int off0 = choff[a * 32 + bx] + wexc[w] + (x - sum4);
    int run = 0;
    #pragma unroll
    for (int i = 0; i < 4; i++) {
        int idx = base + i;
        if (idx < N_NODES) { out[idx] = off0 + run; cur[idx] = off0 + run; }
        run += v[i];
    }
}

__global__ void scatter_targets(const int* __restrict__ tgt, int* __restrict__ tcur,
                                int* __restrict__ tlist) {
    int i = blockIdx.x * 256 + threadIdx.x;
    if (i < T_TGT) {
        int n = tgt[i];
        int p = atomicAdd(&tcur[n], 1);
        tlist[p] = i;
    }
}

// scatter + edge attention numerator exp(leaky(score)) — unshifted exp is
// overflow-safe (score std ~1.1). No denominator atomics: agg sums them.
__global__ __launch_bounds__(256) void scatter_score(const int* __restrict__ mp,
        const int* __restrict__ tcnt, int* __restrict__ ecur,
        int* __restrict__ elist, __bf16* __restrict__ exs,
        const float* __restrict__ proj, int m) {
    int e = blockIdx.x * 256 + threadIdx.x;
    if (e >= EDGES) return;
    int src = mp[2 * e], dst = mp[2 * e + 1];
    if (tcnt[dst] <= 0) return;
    int p = atomicAdd(&ecur[dst], 1);
    elist[p] = src;
    const float* adp = proj + (size_t)dst * 32 + m * 16;
    const float* asp = proj + (size_t)src * 32 + m * 16 + 8;
    float4 ad0 = *(const float4*)(adp), ad1 = *(const float4*)(adp + 4);
    float4 as0 = *(const float4*)(asp), as1 = *(const float4*)(asp + 4);
    float ads[8] = {ad0.x, ad0.y, ad0.z, ad0.w, ad1.x, ad1.y, ad1.z, ad1.w};
    float ass[8] = {as0.x, as0.y, as0.z, as0.w, as1.x, as1.y, as1.z, as1.w};
    bf16x8 exv;
    #pragma unroll
    for (int h = 0; h < 8; h++) {
        float sc = ads[h] + ass[h];
        sc = sc > 0.f ? sc : SLOPE * sc;
        exv[h] = (__bf16)__expf(sc);
    }
    *(bf16x8*)(exs + (size_t)p * 8) = exv;
}

__global__ void build_ulist(const int* __restrict__ tcnt, int* __restrict__ ulist,
                            int* __restrict__ ucount) {
    int n = blockIdx.x * 256 + threadIdx.x;
    if (n < N_NODES && tcnt[n] > 0) {
        int u = atomicAdd(ucount, 1);
        ulist[u] = n;
    }
}

__global__ void cvt_bf16(const float* __restrict__ in, __bf16* __restrict__ out, int n) {
    int i = blockIdx.x * 256 + threadIdx.x;
    if (i < n) out[i] = (__bf16)in[i];
}

// ---------------------------------------------------------------------------
// 4) Aggregation: one wave per (metapath, target-node); single edge pass.
//    Denominator accumulated in-wave (uniform), normalize at the end.
// ---------------------------------------------------------------------------
__global__ __launch_bounds__(256) void agg_kernel(
        const int* __restrict__ ulist, const int* __restrict__ ctrl_i,
        const int* __restrict__ offs,   // [3][N+1]: m0, m1, targets
        const int* __restrict__ esrc,   // [2][E]
        const __bf16* __restrict__ exs, // [2][E][8]
        const float* __restrict__ nf,
        const int* __restrict__ tlist,
        __bf16* hb0, __bf16* hb1) {
    int m = blockIdx.y;
    int wslot = blockIdx.x * 4 + (threadIdx.x >> 6);
    int lane = threadIdx.x & 63;
    int ucount = ctrl_i[0];
    if (wslot >= ucount) return;        // uniform per wave
    int node = __builtin_amdgcn_readfirstlane(ulist[wslot]);  // -> SGPR
    const int* eo = offs + (size_t)m * (N_NODES + 1);
    int e0 = eo[node], e1 = eo[node + 1];
    const int* srcs = esrc + (size_t)m * EDGES;
    const __bf16* exm = exs + (size_t)m * EDGES * 8;
    float acc[8] = {};
    float dacc[8] = {};
    for (int e = e0; e < e1; e++) {
        int s = srcs[e];                               // uniform -> s_load
        bf16x8 pb = *(const bf16x8*)(exm + (size_t)e * 8);  // uniform 16B
        float v = nf[(size_t)s * 64 + lane];           // coalesced vector load
        #pragma unroll
        for (int h = 0; h < 8; h++) {
            float pw = (float)pb[h];
            dacc[h] += pw;
            acc[h] = fmaf(pw, v, acc[h]);
        }
    }
    #pragma unroll
    for (int h = 0; h < 8; h++)
        acc[h] *= (dacc[h] > 0.f) ? 1.0f / dacc[h] : 0.f;
    // write (bf16) to every target slot mapping to this node
    const int* to = offs + (size_t)2 * (N_NODES + 1);
    int t0 = to[node], t1 = to[node + 1];
    __bf16* hb = (m == 0) ? hb0 : hb1;
    for (int ti = t0; ti < t1; ti++) {
        int t = tlist[ti];
        __bf16* dst = hb + (size_t)t * 512;
        #pragma unroll
        for (int h = 0; h < 8; h++) dst[h * 64 + lane] = (__bf16)acc[h];
    }
}

// ---------------------------------------------------------------------------
// 5) Semantic attention scores via bf16 MFMA.
//    2-phase async pipeline: A (hb rows) and B (Wsem) are staged into
//    double-buffered LDS with global_load_lds (width 16) — the DMA path
//    bypasses VGPRs entirely, so the compiler cannot collapse the prefetch.
//    BM=64, BN=128, BK=64; LDS = 2*(8K + 16K) = 48 KB -> 3 blocks/CU.
// ---------------------------------------------------------------------------
__global__ __launch_bounds__(256) void sem_mfma(
        const __bf16* __restrict__ hb,   // [2][T][512]
        const __bf16* __restrict__ Wb,   // [128][512]
        const float* __restrict__ bsem, const float* __restrict__ a_sem,
        float* __restrict__ scores) {
    __shared__ __bf16 As[2][64 * 64];    // 8 KB per buffer
    __shared__ __bf16 Bs[2][128 * 64];   // 16 KB per buffer
    int m = blockIdx.y;
    int tid = threadIdx.x;
    int wave = tid >> 6, lane = tid & 63;
    const __bf16* A0 = hb + (size_t)m * T_TGT * 512 + (size_t)blockIdx.x * 64 * 512;

    int srow = lane >> 3;            // 0..7
    int scol = (lane & 7) * 8;       // element col 0..56

    auto stage = [&](int buf, int k0) {
        #pragma unroll
        for (int j = 0; j < 2; j++) {           // A: 64 rows x 64 k
            int row = j * 32 + wave * 8 + srow;
            const __bf16* gp = A0 + (size_t)row * 512 + k0 + scol;
            __bf16* lp = &As[buf][(j * 32 + wave * 8) * 64];
            __builtin_amdgcn_global_load_lds((const AS1 void*)gp,
                                             (AS3 void*)lp, 16, 0, 0);
        }
        #pragma unroll
        for (int j = 0; j < 4; j++) {           // B: 128 rows x 64 k
            int row = j * 32 + wave * 8 + srow;
            const __bf16* gp = Wb + (size_t)row * 512 + k0 + scol;
            __bf16* lp = &Bs[buf][(j * 32 + wave * 8) * 64];
            __builtin_amdgcn_global_load_lds((const AS1 void*)gp,
                                             (AS3 void*)lp, 16, 0, 0);
        }
    };

    int mrow = lane & 15;
    int kq = lane >> 4;              // 0..3
    f32x4 acc[4][2] = {};

    stage(0, 0);
    __syncthreads();                 // drains vmcnt: buf0 ready
    for (int t = 0; t < 8; t++) {
        int cur = t & 1;
        if (t < 7) stage(cur ^ 1, (t + 1) * 64);
        __builtin_amdgcn_sched_barrier(0);   // keep stage issues above compute
        const __bf16* Ab = &As[cur][0];
        const __bf16* Bb = &Bs[cur][0];
        #pragma unroll
        for (int kk = 0; kk < 2; kk++) {
            int ko = kk * 32 + kq * 8;
            bf16x8 a[4], b[2];
            #pragma unroll
            for (int r = 0; r < 4; r++)
                a[r] = *(const bf16x8*)(Ab + (r * 16 + mrow) * 64 + ko);
            #pragma unroll
            for (int c = 0; c < 2; c++)
                b[c] = *(const bf16x8*)(Bb + (wave * 32 + c * 16 + mrow) * 64 + ko);
            #pragma unroll
            for (int r = 0; r < 4; r++)
                #pragma unroll
                for (int c = 0; c < 2; c++)
                    acc[r][c] = __builtin_amdgcn_mfma_f32_16x16x32_bf16(a[r], b[c], acc[r][c], 0, 0, 0);
        }
        __syncthreads();             // stage(t+1) done + all reads of buf done
    }

    int n0 = wave * 32;
    float tot = 0.f;
    #pragma unroll
    for (int c = 0; c < 2; c++) {
        int col = n0 + c * 16 + (lane & 15);
        float bs = bsem[col], as = a_sem[col];
        #pragma unroll
        for (int r = 0; r < 4; r++)
            #pragma unroll
            for (int j = 0; j < 4; j++) {
                float x = acc[r][c][j] + bs;
                float th = 1.f - 2.f / (__expf(2.f * x) + 1.f);  // tanh, inf-safe
                tot += th * as;
            }
    }
    __shared__ float red[256];
    red[threadIdx.x] = tot;
    __syncthreads();
    for (int s = 128; s; s >>= 1) {
        if (threadIdx.x < s) red[threadIdx.x] += red[threadIdx.x + s];
        __syncthreads();
    }
    if (threadIdx.x == 0) atomicAdd(&scores[m], red[0]);
}

__global__ void beta_kernel(const float* __restrict__ scores, float* __restrict__ beta) {
    if (threadIdx.x == 0) {
        float s0 = scores[0] / (float)T_TGT;
        float s1 = scores[1] / (float)T_TGT;
        float mx = fmaxf(s0, s1);
        float e0 = __expf(s0 - mx), e1 = __expf(s1 - mx);
        float inv = 1.f / (e0 + e1);
        beta[0] = e0 * inv;
        beta[1] = e1 * inv;
    }
}

// ---------------------------------------------------------------------------
// 6) embeddings = b0*h0 + b1*h1 (bf16 in, f32 out) + cls logits.
// ---------------------------------------------------------------------------
__global__ __launch_bounds__(256) void emb_cls(
        const __bf16* __restrict__ hb0, const __bf16* __restrict__ hb1,
        const float* __restrict__ beta, const float* __restrict__ Wcls,
        const float* __restrict__ bcls, float* out_cls, float* out_emb) {
    __shared__ float Wl[8 * 512];
    int tid = threadIdx.x;
    #pragma unroll
    for (int i = 0; i < 16; i++) Wl[tid + i * 256] = Wcls[tid + i * 256];
    __syncthreads();
    int t = blockIdx.x * 4 + (tid >> 6);
    int lane = tid & 63;
    float b0 = beta[0], b1 = beta[1];
    bf16x8 v0 = *(const bf16x8*)(hb0 + (size_t)t * 512 + lane * 8);
    bf16x8 v1 = *(const bf16x8*)(hb1 + (size_t)t * 512 + lane * 8);
    float e[8];
    #pragma unroll
    for (int j = 0; j < 8; j++) e[j] = b0 * (float)v0[j] + b1 * (float)v1[j];
    float* ep = out_emb + (size_t)t * 512 + lane * 8;
    *(float4*)(ep + 0) = make_float4(e[0], e[1], e[2], e[3]);
    *(float4*)(ep + 4) = make_float4(e[4], e[5], e[6], e[7]);
    float pc[8];
    #pragma unroll
    for (int c = 0; c < 8; c++) {
        float4 w0 = *(const float4*)(Wl + c * 512 + lane * 8);
        float4 w1 = *(const float4*)(Wl + c * 512 + lane * 8 + 4);
        pc[c] = e[0] * w0.x + e[1] * w0.y + e[2] * w0.z + e[3] * w0.w
              + e[4] * w1.x + e[5] * w1.y + e[6] * w1.z + e[7] * w1.w;
    }
    #pragma unroll
    for (int off = 32; off; off >>= 1)
        #pragma unroll
        for (int c = 0; c < 8; c++) pc[c] += __shfl_xor(pc[c], off);
    if (lane == 0) {
        #pragma unroll
        for (int c = 0; c < 8; c++) out_cls[(size_t)t * 8 + c] = pc[c] + bcls[c];
    }
}

// ---------------------------------------------------------------------------
extern "C" void kernel_launch(void* const* d_in, const int* in_sizes, int n_in,
                              void* d_out, int out_size, void* d_ws, size_t ws_size,
                              hipStream_t stream) {
    const int* target = (const int*)d_in[0];
    const int* mp0 = (const int*)d_in[1];
    const int* mp1 = (const int*)d_in[2];
    // d_in[3] node_type_mapping unused (types are contiguous ranges)
    const float* feat0 = (const float*)d_in[4];
    const float* W0 = (const float*)d_in[5];
    const float* b0 = (const float*)d_in[6];
    const float* feat1 = (const float*)d_in[7];
    const float* W1 = (const float*)d_in[8];
    const float* b1 = (const float*)d_in[9];
    const float* feat2 = (const float*)d_in[10];
    const float* W2 = (const float*)d_in[11];
    const float* b2 = (const float*)d_in[12];
    const float* natt = (const float*)d_in[13];
    const float* Wsem = (const float*)d_in[14];
    const float* bsem = (const float*)d_in[15];
    const float* asem = (const float*)d_in[16];
    const float* Wcls = (const float*)d_in[17];
    const float* bcls = (const float*)d_in[18];

    char* ws = (char*)d_ws;
    size_t off = 0;
    auto alloc = [&](size_t bytes) -> void* {
        void* p = ws + off;
        off += (bytes + 31) & ~(size_t)31;
        return p;
    };
    float* nf    = (float*)alloc((size_t)N_NODES * 64 * 4);   // 25.6 MB
    float* proj  = (float*)alloc((size_t)N_NODES * 32 * 4);   // 12.8 MB
    int* counts3 = (int*)alloc((size_t)3 * N_NODES * 4);
    int* offs3   = (int*)alloc((size_t)3 * (N_NODES + 1) * 4);
    int* curs3   = (int*)alloc((size_t)3 * N_NODES * 4);
    int* tlist   = (int*)alloc((size_t)T_TGT * 4);
    int* ulist   = (int*)alloc((size_t)N_NODES * 4);
    int* esrc    = (int*)alloc((size_t)2 * EDGES * 4);        // 4 MB
    __bf16* exs  = (__bf16*)alloc((size_t)2 * EDGES * 8 * 2); // 16 MB
    int* partials = (int*)alloc((size_t)3 * 32 * 4);
    int* choff    = (int*)alloc((size_t)3 * 32 * 4);
    int* ctrl    = (int*)alloc(64);
    __bf16* Wsem_b = (__bf16*)alloc((size_t)NSEM * 512 * 2);  // 128 KB
    __bf16* whb  = (__bf16*)alloc((size_t)57344 * 2);         // 112 KB
    __bf16* wlb  = (__bf16*)alloc((size_t)57344 * 2);         // 112 KB
    __bf16* hb   = (__bf16*)alloc((size_t)2 * T_TGT * 512 * 2); // 81.9 MB
    if (off > ws_size) return;  // ws too small: fail loudly (output stays poisoned)

    float* out_cls = (float*)d_out;
    float* out_emb = out_cls + (size_t)T_TGT * NCLS;
    __bf16* hb0 = hb;
    __bf16* hb1 = hb + (size_t)T_TGT * 512;
    float* ctrl_f = (float*)ctrl;
    float* scores = ctrl_f + 1;             // ctrl[0] = ucount
    float* beta = ctrl_f + 3;

    hipMemsetAsync(counts3, 0, (size_t)3 * N_NODES * 4, stream);
    hipMemsetAsync(ctrl, 0, 64, stream);

    cvt_whl<<<dim3(224), 256, 0, stream>>>(W0, W1, W2, whb, wlb);
    proj_mfma<<<dim3(783), 256, 0, stream>>>(feat0, b0, feat1, b1, feat2, b2,
                                             whb, wlb, nf);
    attn_proj<<<dim3(1563), 256, 0, stream>>>(nf, natt, proj);
    cvt_bf16<<<dim3(256), 256, 0, stream>>>(Wsem, Wsem_b, NSEM * 512);

    hist_targets<<<dim3(157), 256, 0, stream>>>(target, counts3 + 2 * N_NODES);
    hist_edges<<<dim3(1954), 256, 0, stream>>>(mp0, counts3 + 2 * N_NODES, counts3);
    hist_edges<<<dim3(1954), 256, 0, stream>>>(mp1, counts3 + 2 * N_NODES, counts3 + N_NODES);
    scan_partial<<<dim3(NCHUNK, 3), 1024, 0, stream>>>(counts3, partials);
    scan_partials<<<dim3(1), 192, 0, stream>>>(partials, choff, offs3);
    scan_final<<<dim3(NCHUNK, 3), 1024, 0, stream>>>(counts3, choff, offs3, curs3);
    scatter_targets<<<dim3(157), 256, 0, stream>>>(target, curs3 + 2 * N_NODES, tlist);
    scatter_score<<<dim3(1954), 256, 0, stream>>>(mp0, counts3 + 2 * N_NODES, curs3,
                                                  esrc, exs, proj, 0);
    scatter_score<<<dim3(1954), 256, 0, stream>>>(mp1, counts3 + 2 * N_NODES, curs3 + N_NODES,
                                                  esrc + EDGES, exs + (size_t)EDGES * 8, proj, 1);
    build_ulist<<<dim3(391), 256, 0, stream>>>(counts3 + 2 * N_NODES, ulist, ctrl);

    agg_kernel<<<dim3(10000, 2), 256, 0, stream>>>(ulist, ctrl, offs3, esrc, exs,
                                                   nf, tlist, hb0, hb1);
    sem_mfma<<<dim3(625, 2), 256, 0, stream>>>(hb, Wsem_b, bsem, asem, scores);
    beta_kernel<<<dim3(1), 64, 0, stream>>>(scores, beta);
    emb_cls<<<dim3(10000), 256, 0, stream>>>(hb0, hb1, beta, Wcls, bcls, out_cls, out_emb);
}